// Round 19
// baseline (525.468 us; speedup 1.0000x reference)
//
#include <hip/hip_runtime.h>
#include <hip/hip_bf16.h>
#include <stdint.h>

typedef __attribute__((ext_vector_type(8))) short short8;
typedef __attribute__((ext_vector_type(4))) float f32x4;
typedef __attribute__((ext_vector_type(4))) int i32x4;

#define DMODEL 768
#define HID    2048
#define MROWS  4096   // 2*2048 tokens

// B-spline constants: h = (4-(-4))/(16-3) = 8/13
#define KINVH  (13.0f/8.0f)
#define KNOT0  (-4.0f - 3.0f*(8.0f/13.0f))

__device__ __forceinline__ unsigned short f2bf(float f) {
  __hip_bfloat16 h = __float2bfloat16(f);   // single v_cvt (RNE)
  return *reinterpret_cast<unsigned short*>(&h);
}

// ---- pack one wave: w[col][k] f32 -> bf16 fragment units (r13 layout) ----
// unit (cb=col/16, kt2=k/32) is 1KB lane-linear: element (q*16+c16) = lane.
template<int DIN>
__device__ __forceinline__ void pack_wave(const float* __restrict__ src,
                                          unsigned short* __restrict__ dst, int gw) {
  constexpr int NK2 = DIN / 2;
  int l   = threadIdx.x & 63;
  int cb  = gw / NK2;
  int kt2 = gw % NK2;
  int c16 = l & 15, q = l >> 4;
  int col = cb * 16 + c16;
  const float* s = src + ((size_t)col * DIN + kt2 * 2 + (q >> 1)) * 16 + (q & 1) * 8;
  float4 v0 = *(const float4*)s;
  float4 v1 = *(const float4*)(s + 4);
  short8 o;
  o[0] = (short)f2bf(v0.x); o[1] = (short)f2bf(v0.y);
  o[2] = (short)f2bf(v0.z); o[3] = (short)f2bf(v0.w);
  o[4] = (short)f2bf(v1.x); o[5] = (short)f2bf(v1.y);
  o[6] = (short)f2bf(v1.z); o[7] = (short)f2bf(v1.w);
  *(short8*)(dst + (((size_t)cb * NK2 + kt2) * 64 + q * 16 + c16) * 8) = o;
}

// ---- phase-1 pack (w1) ----
__global__ void __launch_bounds__(256) conv_pack1(const float* __restrict__ src,
                                                  unsigned short* __restrict__ dst) {
  pack_wave<DMODEL>(src, dst, blockIdx.x * 4 + (threadIdx.x >> 6));
}

// ---- fused phase-2 prep: blocks [0,12288) pack w2; rest do in-place reduce2 ----
__global__ void __launch_bounds__(256) pack2_reduce2(const float* __restrict__ w2,
                                                     unsigned short* __restrict__ dst,
                                                     float4* __restrict__ p, int n4) {
  constexpr int PACK_BLOCKS = ((DMODEL / 16) * (HID / 2)) / 4;   // 12288
  int b = blockIdx.x;
  if (b < PACK_BLOCKS) {
    pack_wave<HID>(w2, dst, b * 4 + (threadIdx.x >> 6));
  } else {
    int i = (b - PACK_BLOCKS) * 256 + threadIdx.x;
    if (i < n4) {
      float4 a = p[i], q = p[i + n4];
      float4 r;
      r.x = a.x + q.x; r.y = a.y + q.y; r.z = a.z + q.z; r.w = a.w + q.w;
      p[i] = r;
    }
  }
}

// ---- split-K=4 reduce: out[i] = sum over 4 planes ----
__global__ void __launch_bounds__(256) reduce4(const float4* __restrict__ p,
                                               float4* __restrict__ out, int n4) {
  int i = blockIdx.x * 256 + threadIdx.x;
  if (i >= n4) return;
  float4 a = p[i], b = p[i + n4], c = p[i + 2 * n4], d = p[i + 3 * n4];
  float4 r;
  r.x = a.x + b.x + c.x + d.x;
  r.y = a.y + b.y + c.y + d.y;
  r.z = a.z + b.z + c.z + d.z;
  r.w = a.w + b.w + c.w + d.w;
  out[i] = r;
}

// ---- fused basis + GEMM: r13 454us skeleton (BK=64, two barriers) ----
// C[n,o] = sum_{d,k} basis(X[n,d])_k * Wb'[o,k]
// Tile: BM=64 x BN, BK=64. 4 waves in 1x4; wave tile 64 x (BN/4);
// FN = BN/64 frags. B direct global->register from packed Wb' (full-cover
// next-step prefetch). A via 8KB swizzled LDS. Slim basis (r17 numerics).
// GEMM1: BN=256 (FN=4, grid 1024 = 4/CU exactly).
// GEMM2: BN=128 (FN=2, grid 1536 — fill fix: was 768=3/CU no-refill).
template<int DIN, int DOUT, int BN, int SPLITK>
__global__ void __launch_bounds__(256, 4)
kan_gemm(const float* __restrict__ X, const unsigned short* __restrict__ Wb,
         float* __restrict__ Out) {
  constexpr int BM  = 64;
  constexpr int FN  = BN / 64;             // frags per wave in N
  constexpr int NK  = (DIN * 16) / 64;
  constexpr int NK2 = DIN / 2;
  constexpr int NKS = NK / SPLITK;
  constexpr int GX  = MROWS / BM;          // 64
  constexpr int GY  = DOUT / BN;
  constexpr int CPX = (GX * GY) / 8;       // nwg%8==0, bijective
  __shared__ __align__(16) char smA[BM * 128];   // 64 rows x 64 bf16 (swizzled) = 8KB

  const int tid  = threadIdx.x;
  const int lane = tid & 63;
  const int wid  = tid >> 6;

  // XCD-chunked remap
  const int d    = blockIdx.x + blockIdx.y * GX;
  const int lf   = (d & 7) * CPX + (d >> 3);
  const int brow = (lf % GX) * BM;
  const int bcol = (lf / GX) * BN;
  const int kt0  = blockIdx.z * NKS;
  const int kt1  = kt0 + NKS;

  f32x4 acc[4][FN];
#pragma unroll
  for (int m = 0; m < 4; ++m)
#pragma unroll
    for (int n = 0; n < FN; ++n) acc[m][n] = (f32x4){0.f, 0.f, 0.f, 0.f};

  // A-fragment LDS addressing (constant per lane) — r13-proven 8-row swizzle
  int a_base[4], a_sw[4];
#pragma unroll
  for (int m = 0; m < 4; ++m) {
    int row   = m * 16 + (lane & 15);
    a_base[m] = row * 128 + ((lane >> 4) * 16);
    a_sw[m]   = (row & 7) << 4;
  }

  // B-fragment pointers: frag n, lane-linear in packed layout
  const unsigned short* bp[FN];
#pragma unroll
  for (int n = 0; n < FN; ++n)
    bp[n] = Wb + ((size_t)(bcol / 16 + wid * FN + n) * NK2 + (size_t)kt0 * 2) * 512
               + lane * 8;

  const int br_ = tid >> 2;        // basis row
  const int bd_ = tid & 3;         // basis d-col within the 4-col step
  const float* xrow = X + (size_t)(brow + br_) * DIN + bd_;

  // ---- prologue: X(kt0) + B(kt0) in flight
  float xcur = xrow[(size_t)kt0 * 4];
  short8 bv[2][FN];
#pragma unroll
  for (int n = 0; n < FN; ++n) {
    bv[0][n] = *(const short8*)(bp[n]);
    bv[1][n] = *(const short8*)(bp[n] + 512);
    bp[n] += 1024;
  }

  for (int kt = kt0; kt < kt1; ++kt) {
    __syncthreads();   // prev A-frag reads done

    // ---- stage A: slim basis (r17-validated numerics), swizzled scatter
    {
      float u  = (xcur - KNOT0) * KINVH;
      float uf = floorf(u);
      int   jj = (int)uf;
      float t  = u - uf;
      float s1 = 1.0f - t;
      float t2 = t * t, t3 = t2 * t;
      float s2 = s1 * s1, s3 = s2 * s1;
      float p0 = s3 * (1.0f / 6.0f);
      float p3 = t3 * (1.0f / 6.0f);
      float p1 = fmaf(0.5f, t3, 2.0f / 3.0f) - t2;
      float p2 = fmaf(0.5f, s3, 2.0f / 3.0f) - s2;

      int base = br_ * 128 + bd_ * 32;
      int sw   = (br_ & 7) << 4;
      *(i32x4*)(smA + (base ^ sw))        = (i32x4){0, 0, 0, 0};
      *(i32x4*)(smA + ((base + 16) ^ sw)) = (i32x4){0, 0, 0, 0};
      unsigned short q0 = f2bf(p0), q1 = f2bf(p1), q2 = f2bf(p2), q3 = f2bf(p3);
      int k0 = jj - 3;
      if ((unsigned)(k0 + 0) < 16u) *(unsigned short*)(smA + ((base + (k0 + 0) * 2) ^ sw)) = q0;
      if ((unsigned)(k0 + 1) < 16u) *(unsigned short*)(smA + ((base + (k0 + 1) * 2) ^ sw)) = q1;
      if ((unsigned)(k0 + 2) < 16u) *(unsigned short*)(smA + ((base + (k0 + 2) * 2) ^ sw)) = q2;
      if ((unsigned)(k0 + 3) < 16u) *(unsigned short*)(smA + ((base + (k0 + 3) * 2) ^ sw)) = q3;
    }

    // prefetch X for next step
    {
      int ktn = (kt + 1 < kt1) ? kt + 1 : kt;
      xcur = xrow[(size_t)ktn * 4];
    }

    __syncthreads();   // A-tile visible

    // ---- compute: per-kk A-frag reads, 2 x (4 x FN) MFMA
#pragma unroll
    for (int kk = 0; kk < 2; ++kk) {
      short8 a[4];
#pragma unroll
      for (int m = 0; m < 4; ++m)
        a[m] = *(const short8*)(smA + ((a_base[m] + kk * 64) ^ a_sw[m]));
#pragma unroll
      for (int m = 0; m < 4; ++m)
#pragma unroll
        for (int n = 0; n < FN; ++n)
          acc[m][n] = __builtin_amdgcn_mfma_f32_16x16x32_bf16(a[m], bv[kk][n], acc[m][n], 0, 0, 0);
    }

    // issue next-step B loads (full cover: barrier + basis phase ahead of use)
    if (kt + 1 < kt1) {
#pragma unroll
      for (int n = 0; n < FN; ++n) {
        bv[0][n] = *(const short8*)(bp[n]);
        bv[1][n] = *(const short8*)(bp[n] + 512);
        bp[n] += 1024;
      }
    }
  }

  // ---- epilogue: C/D layout col=lane&15, row=(lane>>4)*4+q
  float* outp = Out + (size_t)blockIdx.z * MROWS * DOUT;
#pragma unroll
  for (int m = 0; m < 4; ++m)
#pragma unroll
    for (int n = 0; n < FN; ++n)
#pragma unroll
      for (int q = 0; q < 4; ++q) {
        int grow = brow + m * 16 + (lane >> 4) * 4 + q;
        int gcol = bcol + wid * (BN / 4) + n * 16 + (lane & 15);
        outp[(size_t)grow * DOUT + gcol] = acc[m][n][q];
      }
}

extern "C" void kernel_launch(void* const* d_in, const int* in_sizes, int n_in,
                              void* d_out, int out_size, void* d_ws, size_t ws_size,
                              hipStream_t stream) {
  const float* x  = (const float*)d_in[0];   // (2,2048,768) f32 -> (4096,768)
  const float* w1 = (const float*)d_in[1];   // (2048,768,16) f32
  const float* w2 = (const float*)d_in[2];   // (768,2048,16) f32
  float* out = (float*)d_out;                // (4096,768) f32

  // ws timeline (128 MiB):
  //   [0, 48M)   : w1b' (phase 1), then w2b' (phase 2, after GEMM1)
  //   [48M, 80M) : GEMM1 partial plane 0 -> becomes h (f32) after reduce2
  //   [80M, 112M): GEMM1 partial plane 1 (dead after reduce2)
  //   [80M, 128M): GEMM2 partial planes 0..3 (overwrites dead plane 1)
  char* ws = (char*)d_ws;
  unsigned short* wgb   = (unsigned short*)ws;                  // 50,331,648 B
  float*          part1 = (float*)(ws + 50331648);              // 2 x 33,554,432 B
  float*          hbf   = part1;                                // alias: plane 0
  float*          part2 = (float*)(ws + 83886080);              // 4 x 12,582,912 B (end = 128MiB)

  // phase 1: pack w1, GEMM1 (BN=256, split-K=2, grid 1024 = 4/CU)
  conv_pack1<<<((HID / 16) * (DMODEL / 2)) / 4, 256, 0, stream>>>(w1, wgb);
  kan_gemm<DMODEL, HID, 256, 2>
      <<<dim3(MROWS / 64, HID / 256, 2), 256, 0, stream>>>(x, wgb, part1);

  // phase 2 prep (fused): pack w2 into dead w1b' slot + in-place reduce2 of h
  {
    const int hn4 = (MROWS * HID) / 4;               // 2,097,152
    const int packB = ((DMODEL / 16) * (HID / 2)) / 4;   // 12288
    const int redB  = hn4 / 256;                     // 8192
    pack2_reduce2<<<packB + redB, 256, 0, stream>>>(w2, wgb, (float4*)part1, hn4);
  }
  // GEMM2 (BN=128, split-K=4, grid 1536 — fill fix) + reduce
  kan_gemm<HID, DMODEL, 128, 4>
      <<<dim3(MROWS / 64, DMODEL / 128, 4), 256, 0, stream>>>(hbf, wgb, part2);
  const int rn4 = (MROWS * DMODEL) / 4;      // 786,432
  reduce4<<<rn4 / 256, 256, 0, stream>>>((const float4*)part2, (float4*)out, rn4);
}

// Round 20
// 443.560 us; speedup vs baseline: 1.1847x; 1.1847x over previous
//
#include <hip/hip_runtime.h>
#include <hip/hip_bf16.h>
#include <stdint.h>

typedef __attribute__((ext_vector_type(8))) short short8;
typedef __attribute__((ext_vector_type(4))) float f32x4;
typedef __attribute__((ext_vector_type(4))) int i32x4;

#define DMODEL 768
#define HID    2048
#define MROWS  4096   // 2*2048 tokens

// B-spline constants: h = (4-(-4))/(16-3) = 8/13
#define KINVH  (13.0f/8.0f)
#define KNOT0  (-4.0f - 3.0f*(8.0f/13.0f))

__device__ __forceinline__ unsigned short f2bf(float f) {
  __hip_bfloat16 h = __float2bfloat16(f);   // single v_cvt (RNE)
  return *reinterpret_cast<unsigned short*>(&h);
}

// ---- pack one wave: w[col][k] f32 -> bf16 fragment units (r13 layout) ----
// unit (cb=col/16, kt2=k/32) is 1KB lane-linear: element (q*16+c16) = lane.
template<int DIN>
__device__ __forceinline__ void pack_wave(const float* __restrict__ src,
                                          unsigned short* __restrict__ dst, int gw) {
  constexpr int NK2 = DIN / 2;
  int l   = threadIdx.x & 63;
  int cb  = gw / NK2;
  int kt2 = gw % NK2;
  int c16 = l & 15, q = l >> 4;
  int col = cb * 16 + c16;
  const float* s = src + ((size_t)col * DIN + kt2 * 2 + (q >> 1)) * 16 + (q & 1) * 8;
  float4 v0 = *(const float4*)s;
  float4 v1 = *(const float4*)(s + 4);
  short8 o;
  o[0] = (short)f2bf(v0.x); o[1] = (short)f2bf(v0.y);
  o[2] = (short)f2bf(v0.z); o[3] = (short)f2bf(v0.w);
  o[4] = (short)f2bf(v1.x); o[5] = (short)f2bf(v1.y);
  o[6] = (short)f2bf(v1.z); o[7] = (short)f2bf(v1.w);
  *(short8*)(dst + (((size_t)cb * NK2 + kt2) * 64 + q * 16 + c16) * 8) = o;
}

// ---- phase-1 pack (w1) ----
__global__ void __launch_bounds__(256) conv_pack1(const float* __restrict__ src,
                                                  unsigned short* __restrict__ dst) {
  pack_wave<DMODEL>(src, dst, blockIdx.x * 4 + (threadIdx.x >> 6));
}

// ---- fused phase-2 prep: blocks [0,12288) pack w2; rest do in-place reduce2 ----
__global__ void __launch_bounds__(256) pack2_reduce2(const float* __restrict__ w2,
                                                     unsigned short* __restrict__ dst,
                                                     float4* __restrict__ p, int n4) {
  constexpr int PACK_BLOCKS = ((DMODEL / 16) * (HID / 2)) / 4;   // 12288
  int b = blockIdx.x;
  if (b < PACK_BLOCKS) {
    pack_wave<HID>(w2, dst, b * 4 + (threadIdx.x >> 6));
  } else {
    int i = (b - PACK_BLOCKS) * 256 + threadIdx.x;
    if (i < n4) {
      float4 a = p[i], q = p[i + n4];
      float4 r;
      r.x = a.x + q.x; r.y = a.y + q.y; r.z = a.z + q.z; r.w = a.w + q.w;
      p[i] = r;
    }
  }
}

// ---- split-K=4 reduce: out[i] = sum over 4 planes ----
__global__ void __launch_bounds__(256) reduce4(const float4* __restrict__ p,
                                               float4* __restrict__ out, int n4) {
  int i = blockIdx.x * 256 + threadIdx.x;
  if (i >= n4) return;
  float4 a = p[i], b = p[i + n4], c = p[i + 2 * n4], d = p[i + 3 * n4];
  float4 r;
  r.x = a.x + b.x + c.x + d.x;
  r.y = a.y + b.y + c.y + d.y;
  r.z = a.z + b.z + c.z + d.z;
  r.w = a.w + b.w + c.w + d.w;
  out[i] = r;
}

// ---- fused basis + GEMM: the r13 454us skeleton (proven optimum) ----
// C[n,o] = sum_{d,k} basis(X[n,d])_k * Wb'[o,k]
// Tile: BM=64 x BN=256, BK=64. 4 waves in 1x4; wave tile 64x64 (FM=FN=4).
// A via 8KB swizzled LDS (two __syncthreads per step); B direct
// global->register from fragment-packed Wb' (next-step prefetch with full
// barrier+basis cover). 64 VGPR + 64 AGPR = 128 -> 4 waves/SIMD.
// Every probed perturbation regresses: BN=128 (redundancy, r3/r19),
// BK=128 (uncovered mid-step B reload, r18), 32x32 MFMA (bank conflicts,
// r10/r17), LDS/reg double-buffer (spill, r12/r15/r16), relaxed barriers
// (null, r14), atomics (r5), B-via-LDS (LDS pipe, r7), B-gather (r9).
template<int DIN, int DOUT, int SPLITK>
__global__ void __launch_bounds__(256, 4)
kan_gemm(const float* __restrict__ X, const unsigned short* __restrict__ Wb,
         float* __restrict__ Out) {
  constexpr int BM  = 64;
  constexpr int BN  = 256;
  constexpr int NK  = (DIN * 16) / 64;
  constexpr int NK2 = DIN / 2;
  constexpr int NKS = NK / SPLITK;
  constexpr int GX  = MROWS / BM;          // 64
  constexpr int GY  = DOUT / BN;
  constexpr int CPX = (GX * GY) / 8;       // nwg%8==0, bijective
  __shared__ __align__(16) char smA[BM * 128];   // 64 rows x 64 bf16 (swizzled) = 8KB

  const int tid  = threadIdx.x;
  const int lane = tid & 63;
  const int wid  = tid >> 6;

  // XCD-chunked remap
  const int d    = blockIdx.x + blockIdx.y * GX;
  const int lf   = (d & 7) * CPX + (d >> 3);
  const int brow = (lf % GX) * BM;
  const int bcol = (lf / GX) * BN;
  const int kt0  = blockIdx.z * NKS;
  const int kt1  = kt0 + NKS;

  f32x4 acc[4][4];
#pragma unroll
  for (int m = 0; m < 4; ++m)
#pragma unroll
    for (int n = 0; n < 4; ++n) acc[m][n] = (f32x4){0.f, 0.f, 0.f, 0.f};

  // A-fragment LDS addressing (constant per lane) — r13-proven 8-row swizzle
  int a_base[4], a_sw[4];
#pragma unroll
  for (int m = 0; m < 4; ++m) {
    int row   = m * 16 + (lane & 15);
    a_base[m] = row * 128 + ((lane >> 4) * 16);
    a_sw[m]   = (row & 7) << 4;
  }

  // B-fragment pointers: frag n, lane-linear in packed layout
  const unsigned short* bp[4];
#pragma unroll
  for (int n = 0; n < 4; ++n)
    bp[n] = Wb + ((size_t)(bcol / 16 + wid * 4 + n) * NK2 + (size_t)kt0 * 2) * 512
               + lane * 8;

  const int br_ = tid >> 2;        // basis row
  const int bd_ = tid & 3;         // basis d-col within the 4-col step
  const float* xrow = X + (size_t)(brow + br_) * DIN + bd_;

  // ---- prologue: X(kt0) + B(kt0) in flight
  float xcur = xrow[(size_t)kt0 * 4];
  short8 bv[2][4];
#pragma unroll
  for (int n = 0; n < 4; ++n) {
    bv[0][n] = *(const short8*)(bp[n]);
    bv[1][n] = *(const short8*)(bp[n] + 512);
    bp[n] += 1024;
  }

  for (int kt = kt0; kt < kt1; ++kt) {
    __syncthreads();   // prev A-frag reads done

    // ---- stage A: slim basis (Horner + symmetry, r17-validated), swizzled scatter
    {
      float u  = (xcur - KNOT0) * KINVH;
      float uf = floorf(u);
      int   jj = (int)uf;
      float t  = u - uf;
      float s1 = 1.0f - t;
      float t2 = t * t, t3 = t2 * t;
      float s2 = s1 * s1, s3 = s2 * s1;
      float p0 = s3 * (1.0f / 6.0f);
      float p3 = t3 * (1.0f / 6.0f);
      float p1 = fmaf(0.5f, t3, 2.0f / 3.0f) - t2;
      float p2 = fmaf(0.5f, s3, 2.0f / 3.0f) - s2;

      int base = br_ * 128 + bd_ * 32;
      int sw   = (br_ & 7) << 4;
      *(i32x4*)(smA + (base ^ sw))        = (i32x4){0, 0, 0, 0};
      *(i32x4*)(smA + ((base + 16) ^ sw)) = (i32x4){0, 0, 0, 0};
      unsigned short q0 = f2bf(p0), q1 = f2bf(p1), q2 = f2bf(p2), q3 = f2bf(p3);
      int k0 = jj - 3;
      if ((unsigned)(k0 + 0) < 16u) *(unsigned short*)(smA + ((base + (k0 + 0) * 2) ^ sw)) = q0;
      if ((unsigned)(k0 + 1) < 16u) *(unsigned short*)(smA + ((base + (k0 + 1) * 2) ^ sw)) = q1;
      if ((unsigned)(k0 + 2) < 16u) *(unsigned short*)(smA + ((base + (k0 + 2) * 2) ^ sw)) = q2;
      if ((unsigned)(k0 + 3) < 16u) *(unsigned short*)(smA + ((base + (k0 + 3) * 2) ^ sw)) = q3;
    }

    // prefetch X for next step
    {
      int ktn = (kt + 1 < kt1) ? kt + 1 : kt;
      xcur = xrow[(size_t)ktn * 4];
    }

    __syncthreads();   // A-tile visible

    // ---- compute: per-kk A-frag reads, 2 x (4x4) MFMA
#pragma unroll
    for (int kk = 0; kk < 2; ++kk) {
      short8 a[4];
#pragma unroll
      for (int m = 0; m < 4; ++m)
        a[m] = *(const short8*)(smA + ((a_base[m] + kk * 64) ^ a_sw[m]));
#pragma unroll
      for (int m = 0; m < 4; ++m)
#pragma unroll
        for (int n = 0; n < 4; ++n)
          acc[m][n] = __builtin_amdgcn_mfma_f32_16x16x32_bf16(a[m], bv[kk][n], acc[m][n], 0, 0, 0);
    }

    // issue next-step B loads (full cover: barrier + basis phase ahead of use)
    if (kt + 1 < kt1) {
#pragma unroll
      for (int n = 0; n < 4; ++n) {
        bv[0][n] = *(const short8*)(bp[n]);
        bv[1][n] = *(const short8*)(bp[n] + 512);
        bp[n] += 1024;
      }
    }
  }

  // ---- epilogue: C/D layout col=lane&15, row=(lane>>4)*4+q
  float* outp = Out + (size_t)blockIdx.z * MROWS * DOUT;
#pragma unroll
  for (int m = 0; m < 4; ++m)
#pragma unroll
    for (int n = 0; n < 4; ++n)
#pragma unroll
      for (int q = 0; q < 4; ++q) {
        int grow = brow + m * 16 + (lane >> 4) * 4 + q;
        int gcol = bcol + wid * 64 + n * 16 + (lane & 15);
        outp[(size_t)grow * DOUT + gcol] = acc[m][n][q];
      }
}

extern "C" void kernel_launch(void* const* d_in, const int* in_sizes, int n_in,
                              void* d_out, int out_size, void* d_ws, size_t ws_size,
                              hipStream_t stream) {
  const float* x  = (const float*)d_in[0];   // (2,2048,768) f32 -> (4096,768)
  const float* w1 = (const float*)d_in[1];   // (2048,768,16) f32
  const float* w2 = (const float*)d_in[2];   // (768,2048,16) f32
  float* out = (float*)d_out;                // (4096,768) f32

  // ws timeline (128 MiB):
  //   [0, 48M)   : w1b' (phase 1), then w2b' (phase 2, after GEMM1)
  //   [48M, 80M) : GEMM1 partial plane 0 -> becomes h (f32) after reduce2
  //   [80M, 112M): GEMM1 partial plane 1 (dead after reduce2)
  //   [80M, 128M): GEMM2 partial planes 0..3 (overwrites dead plane 1)
  char* ws = (char*)d_ws;
  unsigned short* wgb   = (unsigned short*)ws;                  // 50,331,648 B
  float*          part1 = (float*)(ws + 50331648);              // 2 x 33,554,432 B
  float*          hbf   = part1;                                // alias: plane 0
  float*          part2 = (float*)(ws + 83886080);              // 4 x 12,582,912 B (end = 128MiB)

  // phase 1: pack w1, GEMM1 (BN=256, split-K=2, grid 1024 = 4/CU)
  conv_pack1<<<((HID / 16) * (DMODEL / 2)) / 4, 256, 0, stream>>>(w1, wgb);
  kan_gemm<DMODEL, HID, 2>
      <<<dim3(MROWS / 64, HID / 256, 2), 256, 0, stream>>>(x, wgb, part1);

  // phase 2 prep (fused): pack w2 into dead w1b' slot + in-place reduce2 of h
  {
    const int hn4 = (MROWS * HID) / 4;               // 2,097,152
    const int packB = ((DMODEL / 16) * (HID / 2)) / 4;   // 12288
    const int redB  = hn4 / 256;                     // 8192
    pack2_reduce2<<<packB + redB, 256, 0, stream>>>(w2, wgb, (float4*)part1, hn4);
  }
  // GEMM2 (BN=256, split-K=4 — the r13-proven config) + reduce
  kan_gemm<HID, DMODEL, 4>
      <<<dim3(MROWS / 64, DMODEL / 256, 4), 256, 0, stream>>>(hbf, wgb, part2);
  const int rn4 = (MROWS * DMODEL) / 4;      // 786,432
  reduce4<<<rn4 / 256, 256, 0, stream>>>((const float4*)part2, (float4*)out, rn4);
}